// Round 6
// baseline (227.394 us; speedup 1.0000x reference)
//
#include <hip/hip_runtime.h>

constexpr int Bn  = 4;
constexpr int Sn  = 1024;
constexpr int Dn  = 1024;
constexpr int Hn  = 16;
constexpr int HDn = 64;

using short8   = __attribute__((ext_vector_type(8))) short;
using float4v  = __attribute__((ext_vector_type(4))) float;
using float16v = __attribute__((ext_vector_type(16))) float;

__device__ __forceinline__ ushort f2bf(float f) {
    union { float f; unsigned u; } v; v.f = f;
    unsigned r = v.u + 0x7fff + ((v.u >> 16) & 1);   // RNE
    return (ushort)(r >> 16);
}

__device__ __forceinline__ void gload16(const void* g, void* l) {
    __builtin_amdgcn_global_load_lds(
        (const __attribute__((address_space(1))) void*)g,
        (__attribute__((address_space(3))) void*)l, 16, 0, 0);
}

// ---------------------------------------------------------------------------
// prep — ONE dispatch, 3328 blocks:
//   [0,2048)    convert_x: x fp32 -> xb bf16
//   [2048,2816) transpose_w: W (KxN fp32) -> Wt (NxK bf16), 64x64 LDS tiles
//   [2816,3328) mask+copy: adj -> out passthrough AND pair-halfword masks in
//               PV-pack fragment order (512 blocks: one 128q x 64k tile each)
// Mask layout (R7/R10-proven): dst = Mb + ((((b*8+qt)*16+kt)*4+w)*64+lane)*16;
// word mt*8+pr covers keys kt*64+mt*32+(2pr&3)+8*(2pr>>2)+4*hi+{0,1},
// q = qt*128+w*32+(lane&31).
// ---------------------------------------------------------------------------
__global__ __launch_bounds__(256) void prep(
    const float* __restrict__ x,
    const float* __restrict__ Wq, const float* __restrict__ Wk,
    const float* __restrict__ Wv, const float* __restrict__ adj,
    ushort* __restrict__ xb, ushort* __restrict__ Wt, uint* __restrict__ Mb,
    float* __restrict__ out)
{
    const int bx  = blockIdx.x;
    const int tid = threadIdx.x;
    __shared__ __align__(16) ushort pool[64 * 72];   // 9216 B, aliased by msk

    if (bx < 2048) {
        // ---- convert_x ----
        const size_t i = ((size_t)bx * 256 + tid) * 8;
        float4 a = *(const float4*)&x[i];
        float4 b = *(const float4*)&x[i + 4];
        ushort o[8] = {f2bf(a.x), f2bf(a.y), f2bf(a.z), f2bf(a.w),
                       f2bf(b.x), f2bf(b.y), f2bf(b.z), f2bf(b.w)};
        *(uint4*)&xb[i] = *(const uint4*)o;
    } else if (bx < 2816) {
        // ---- transpose_w ----
        const int idx = bx - 2048;
        const int which = idx >> 8, rem = idx & 255;
        const float* __restrict__ W = (which == 0) ? Wq : (which == 1) ? Wk : Wv;
        ushort* __restrict__ O = Wt + (size_t)which * Dn * Dn;
        const int k0 = (rem & 15) * 64, n0 = (rem >> 4) * 64;
        ushort* T = pool;

        const int kl = tid >> 4, nl = (tid & 15) * 4;
#pragma unroll
        for (int p = 0; p < 4; ++p) {
            float4 w4 = *(const float4*)&W[(size_t)(k0 + p * 16 + kl) * Dn + n0 + nl];
            T[(nl + 0) * 72 + p * 16 + kl] = f2bf(w4.x);
            T[(nl + 1) * 72 + p * 16 + kl] = f2bf(w4.y);
            T[(nl + 2) * 72 + p * 16 + kl] = f2bf(w4.z);
            T[(nl + 3) * 72 + p * 16 + kl] = f2bf(w4.w);
        }
        __syncthreads();
        const int nr = tid >> 2, kc = (tid & 3) * 16;
        uint4 u0 = *(const uint4*)&T[nr * 72 + kc];
        uint4 u1 = *(const uint4*)&T[nr * 72 + kc + 8];
        *(uint4*)&O[(size_t)(n0 + nr) * Dn + k0 + kc]     = u0;
        *(uint4*)&O[(size_t)(n0 + nr) * Dn + k0 + kc + 8] = u1;
    } else {
        // ---- mask + adj->out copy: idx = ((b*8+qt)*16+kt) ----
        const int idx = bx - 2816;                 // 0..511
        const int kt = idx & 15, qt = (idx >> 4) & 7, b = idx >> 7;
        char* msk = (char*)pool;                   // [128][68], 8704 B <= 9216

        float* ocopy = out + (size_t)Bn * Sn * Dn;
        const int r16 = tid >> 4, c4 = (tid & 15) * 4;
#pragma unroll
        for (int p = 0; p < 8; ++p) {
            const int row = p * 16 + r16;
            const size_t gi = ((size_t)b * Sn + qt * 128 + row) * Sn + kt * 64 + c4;
            float4 a = *(const float4*)&adj[gi];
            *(float4*)&ocopy[gi] = a;
            char* mr = &msk[row * 68 + c4];
            mr[0] = a.x >= 0.5f; mr[1] = a.y >= 0.5f;
            mr[2] = a.z >= 0.5f; mr[3] = a.w >= 0.5f;
        }
        __syncthreads();

        const int lane = tid & 63, w = tid >> 6;
        const int col = lane & 31, hi = lane >> 5;
        uint words[16];
#pragma unroll
        for (int mt = 0; mt < 2; ++mt)
#pragma unroll
            for (int pr = 0; pr < 8; ++pr) {
                const int r0 = 2 * pr;
                const int kl = mt * 32 + (r0 & 3) + 8 * (r0 >> 2) + 4 * hi;
                const char* mr = &msk[(w * 32 + col) * 68];
                words[mt * 8 + pr] = (mr[kl]     ? 0x0000FFFFu : 0u) |
                                     (mr[kl + 1] ? 0xFFFF0000u : 0u);
            }
        uint* dst = Mb + ((((size_t)(b * 8 + qt) * 16 + kt) * 4 + w) * 64 + lane) * 16;
#pragma unroll
        for (int c = 0; c < 4; ++c)
            *(uint4*)&dst[c * 4] =
                make_uint4(words[c*4], words[c*4+1], words[c*4+2], words[c*4+3]);
    }
}

// ---------------------------------------------------------------------------
// bf16 MFMA GEMM (R16): A via LDS (swizzled, distance-2 counted vmcnt),
// B DIRECT global->VGPR (no LDS), register-double-buffered 1 step ahead.
// Rationale: R3/R4/R5 all landed at 43 µs / MfmaUtil 22% across three
// different pipeline schedules -> LDS-pipe-bound, not schedule-bound
// (per CU per K-step: 96 KB ds_read + 48 KB gload_lds writes ~ 1730 cy vs
// MFMA ~930 cy). Dropping B from LDS halves LDS traffic (72 KB ~ 850 cy),
// putting the MFMA pipe in charge. LDS 48 KB -> 16 KB.
// B-frag load: 16 rows x 64 B contiguous per instr, L2-served, prefetched
// one K-step ahead; even/odd unroll avoids a reg-copy that would drag the
// wait early. vmcnt(6) at step top: in-order retirement => 2 oldest
// (A(k)'s gload_lds pair) landed; A(k+1),B(k) (<=6) stay in flight.
//  - XCD-chunked 1D grid (768): each XCD owns 4 contiguous A-panels (by).
// ---------------------------------------------------------------------------
__global__ __launch_bounds__(256) void qkv_gemm(
    const ushort* __restrict__ xb, const ushort* __restrict__ Wt,
    const float* __restrict__ bq, const float* __restrict__ bk,
    const float* __restrict__ bv,
    ushort* __restrict__ Qb, ushort* __restrict__ Kb, ushort* __restrict__ Vb)
{
    // XCD-chunked decode: xcd = n&7 owns v in [xcd*96, xcd*96+96)
    // v = by*24 + (which*8 + bx):  by-major => A-panel reuse within XCD L2
    const int n  = blockIdx.x;                // 0..767
    const int v  = (n & 7) * 96 + (n >> 3);
    const int by = v / 24;                    // 0..31
    const int rr = v - by * 24;
    const int bxi   = rr & 7;                 // 0..7
    const int which = rr >> 3;                // 0..2

    const ushort* __restrict__ Bw   = Wt + (size_t)which * Dn * Dn;
    const float* __restrict__  bias = (which == 0) ? bq : (which == 1) ? bk : bv;
    ushort* __restrict__       Out  = (which == 0) ? Qb : (which == 1) ? Kb : Vb;
    const float scale = (which == 0) ? 0.18033688011112042f : 1.0f;  // 0.125*log2(e)

    const int n0   = bxi * 128;
    const int m0   = by * 128;
    const int tid  = threadIdx.x;
    const int wave = tid >> 6;
    const int lane = tid & 63;
    const int wm   = wave >> 1;
    const int wn   = wave & 1;

    // A only: [buf][128*32], 8 KB per buffer, 16 KB total
    __shared__ __align__(16) ushort As[2][128 * 32];

    const int L0 = tid;
    const int r0s = L0 >> 2, c0s = ((L0 & 3) ^ ((L0 >> 3) & 3)) * 8;  // swizzled src chunk
    const int L1 = tid + 256;
    const int r1s = L1 >> 2, c1s = ((L1 & 3) ^ ((L1 >> 3) & 3)) * 8;

    const ushort* pA0 = &xb[(size_t)(m0 + r0s) * Dn + c0s];
    const ushort* pA1 = &xb[(size_t)(m0 + r1s) * Dn + c1s];

    const int mlane = lane & 15;
    // A read-side inverse swizzle: chunk = (lane>>4) ^ ((row>>1)&3)
    const int kg  = (((lane >> 4) ^ ((mlane >> 1) & 3))) * 8;
    // B direct-load chunk (no swizzle needed)
    const int kg0 = (lane >> 4) * 8;

    // B row base for this wave/lane: rows n0+wn*64+j*16+mlane, j stride 16*Dn
    const ushort* pB = &Bw[(size_t)(n0 + wn * 64 + mlane) * Dn + kg0];

    float4v acc[4][4];
    const float4v z4 = {0.f, 0.f, 0.f, 0.f};
#pragma unroll
    for (int i = 0; i < 4; ++i)
#pragma unroll
        for (int j = 0; j < 4; ++j) acc[i][j] = z4;

    auto stageA = [&](int c) {
        char* ab = (char*)As + c * 8192 + wave * 1024;
        gload16(pA0, ab);
        gload16(pA1, ab + 4096);
        pA0 += 32; pA1 += 32;
    };

    constexpr int NT = Dn / 32;     // 32 K-steps

    // one K-step: wait A(k), read A-frags, free buf, stage A(k+2) into buf,
    // load B(k+1) into bnext, MFMA with bcur.
    auto kstep = [&](int k, int cur, short8 (&bcur)[4], short8 (&bnext)[4]) {
        asm volatile("s_waitcnt vmcnt(6)" ::: "memory");   // A(k) landed (own)
        __builtin_amdgcn_s_barrier();                      // ...for all waves
        __builtin_amdgcn_sched_barrier(0);
        short8 af[4];
#pragma unroll
        for (int i = 0; i < 4; ++i)
            af[i] = *(const short8*)&As[cur][(wm * 64 + i * 16 + mlane) * 32 + kg];
        asm volatile("s_waitcnt lgkmcnt(0)" ::: "memory"); // own reads retired
        __builtin_amdgcn_sched_barrier(0);
        __builtin_amdgcn_s_barrier();                      // buf cur free (all)
        __builtin_amdgcn_sched_barrier(0);
        if (k + 2 < NT) stageA(cur);                       // A(k+2) -> buf cur
        if (k + 1 < NT) {
            const int kn = (k + 1) * 32;
#pragma unroll
            for (int j = 0; j < 4; ++j)
                bnext[j] = *(const short8*)&pB[(size_t)j * 16 * Dn + kn];
        }
        __builtin_amdgcn_s_setprio(1);
#pragma unroll
        for (int i = 0; i < 4; ++i)
#pragma unroll
            for (int j = 0; j < 4; ++j)
                acc[i][j] = __builtin_amdgcn_mfma_f32_16x16x32_bf16(af[i], bcur[j], acc[i][j], 0, 0, 0);
        __builtin_amdgcn_s_setprio(0);
    };

    // prologue: A(0), A(1) staged; B(0) loaded
    stageA(0); stageA(1);
    short8 b0[4], b1[4];
#pragma unroll
    for (int j = 0; j < 4; ++j)
        b0[j] = *(const short8*)&pB[(size_t)j * 16 * Dn];

    for (int k = 0; k < NT; k += 2) {      // even/odd: no bcur=bnext reg copy
        kstep(k,     0, b0, b1);
        kstep(k + 1, 1, b1, b0);
    }

    const int rb  = (lane >> 4) * 4;
    const int col = lane & 15;
#pragma unroll
    for (int j = 0; j < 4; ++j) {
        const int nn = n0 + wn * 64 + j * 16 + col;
        const float bias_n = bias[nn];
        const int h  = nn >> 6;
        const int hd = nn & 63;
#pragma unroll
        for (int i = 0; i < 4; ++i) {
#pragma unroll
            for (int r = 0; r < 4; ++r) {
                const int m = m0 + wm * 64 + i * 16 + rb + r;
                const int b = m >> 10;
                const int s = m & 1023;
                size_t addr;
                if (which == 2)
                    addr = (((size_t)(b * Hn + h)) * HDn + hd) * Sn + s;   // V transposed
                else
                    addr = (((size_t)(b * Hn + h)) * Sn + s) * HDn + hd;
                Out[addr] = f2bf((acc[i][j][r] + bias_n) * scale);
            }
        }
    }
}

// ---------------------------------------------------------------------------
// MFMA flash attention, split-K over keys:
// Block = 512 threads (8 waves) = 128 q of one (b,h).
//   waves 0-3 (group 0): keys   0..511; waves 4-7 (group 1): keys 512..1023
// Mask loaded at top of each kt iteration (independent load, latency covered
// by QK^T cluster — R2's explicit one-ahead prefetch caused ~96 MB/dispatch
// of scratch-spill WRITE traffic and a 25 µs regression; do NOT re-add).
// Pack via v_permlane32_swap_b32 (one swap yields both output words);
// s_setprio(1) around MFMA clusters (T5).
// Cross-group combine via one LDS exchange (exp2 softmax has no running
// max -> pure (o,l) add). XCD swizzle: co-(b,h) blocks share an XCD L2.
// ---------------------------------------------------------------------------
__global__ __launch_bounds__(512, 4) void attn_mfma(
    const ushort* __restrict__ Q, const ushort* __restrict__ K,
    const ushort* __restrict__ Vt, const uint* __restrict__ Mw,
    float* __restrict__ out)
{
    // XCD-aware decode: n%8 == bh%8 -> co-(b,h) blocks share an XCD L2
    const int n  = blockIdx.x;                 // 0..511
    const int qt = (n >> 3) & 7;
    const int bh = (n & 7) | ((n >> 6) << 3);  // 0..63
    const int h  = bh & 15;
    const int b  = bh >> 4;

    const int tid  = threadIdx.x;
    const int w    = tid >> 6, lane = tid & 63;
    const int g    = w >> 2;                   // key-half group
    const int wq   = w & 3;                    // q-subtile within block
    const int col  = lane & 31, hi = lane >> 5;

    const size_t hb = ((size_t)(b * Hn + h)) * Sn * HDn;
    const ushort* Kg = K + hb;          // [key][dim]
    const ushort* Vg = Vt + hb;         // [dim][key]

    // [group][buf][K=0/V=1][64*72] = 73728 B
    __shared__ __align__(16) ushort KV[2][2][2][64 * 72];

    short8 qf[4];
#pragma unroll
    for (int kp = 0; kp < 4; ++kp)
        qf[kp] = *(const short8*)&Q[hb +
            (size_t)(qt * 128 + wq * 32 + col) * HDn + kp * 16 + hi * 8];

    float16v o_[2];
#pragma unroll
    for (int dt = 0; dt < 2; ++dt)
#pragma unroll
        for (int r = 0; r < 16; ++r) o_[dt][r] = 0.f;
    float ls = 0.f;

    // staging: each group's 256 threads load that group's 64-key K/V tile
    const int t  = tid & 255;
    const int c0 = t, c1 = t + 256;
    const int la0 = (c0 >> 3) * 72 + (c0 & 7) * 8;
    const int la1 = (c1 >> 3) * 72 + (c1 & 7) * 8;
    const int kb  = g * 8;                     // first key-tile of this group

    uint4 k0 = *(const uint4*)&Kg[(size_t)(kb * 64 + (c0 >> 3)) * HDn + (c0 & 7) * 8];
    uint4 k1 = *(const uint4*)&Kg[(size_t)(kb * 64 + (c1 >> 3)) * HDn + (c1 & 7) * 8];
    uint4 v0 = *(const uint4*)&Vg[(size_t)(c0 >> 3) * Sn + kb * 64 + (c0 & 7) * 8];
    uint4 v1 = *(const uint4*)&Vg[(size_t)(c1 >> 3) * Sn + kb * 64 + (c1 & 7) * 8];
    *(uint4*)&KV[g][0][0][la0] = k0;  *(uint4*)&KV[g][0][0][la1] = k1;
    *(uint4*)&KV[g][0][1][la0] = v0;  *(uint4*)&KV[g][0][1][la1] = v1;
    __syncthreads();

    const uint* mbase = Mw + ((size_t)((b * 8 + qt) * 16) * 4 + wq) * 1024 + lane * 16;

    for (int kt = 0; kt < 8; ++kt) {
        const int cur = kt & 1;
        if (kt < 7) {
            const int nk = (kb + kt + 1) * 64;
            k0 = *(const uint4*)&Kg[(size_t)(nk + (c0 >> 3)) * HDn + (c0 & 7) * 8];
            k1 = *(const uint4*)&Kg[(size_t)(nk + (c1 >> 3)) * HDn + (c1 & 7) * 8];
            v0 = *(const uint4*)&Vg[(size_t)(c0 >> 3) * Sn + nk + (c0 & 7) * 8];
            v1 = *(const uint4*)&Vg[(size_t)(c1 >> 3) * Sn + nk + (c1 & 7) * 8];
        }
        const uint* mp = mbase + (size_t)(kb + kt) * 4096;
        uint4 mk4[4];
        mk4[0] = *(const uint4*)(mp);
        mk4[1] = *(const uint4*)(mp + 4);
        mk4[2] = *(const uint4*)(mp + 8);
        mk4[3] = *(const uint4*)(mp + 12);
        const uint* mka = (const uint*)mk4;   // [mt*8 + pr]

#pragma unroll
        for (int mt = 0; mt < 2; ++mt) {
            float16v s_;
#pragma unroll
            for (int r = 0; r < 16; ++r) s_[r] = 0.f;
            __builtin_amdgcn_s_setprio(1);
#pragma unroll
            for (int kp = 0; kp < 4; ++kp) {
                short8 ak = *(const short8*)&KV[g][cur][0][(mt * 32 + col) * 72 + kp * 16 + hi * 8];
                s_ = __builtin_amdgcn_mfma_f32_32x32x16_bf16(ak, qf[kp], s_, 0, 0, 0);
            }
            __builtin_amdgcn_s_setprio(0);

            unsigned up[8];
#pragma unroll
            for (int pr = 0; pr < 8; ++pr) {
                const unsigned e0 = __float_as_uint(exp2f(s_[2 * pr]))     + 0x8000u;
                const unsigned e1 = __float_as_uint(exp2f(s_[2 * pr + 1])) + 0x8000u;
                const unsigned u  = __builtin_amdgcn_perm(e1, e0, 0x07060302u) & mka[mt * 8 + pr];
                up[pr] = u;
                ls += __uint_as_float(u << 16) + __uint_as_float(u & 0xffff0000u);
            }

            __builtin_amdgcn_s_setprio(1);
#pragma unroll
            for (int kh = 0; kh < 2; ++kh) {
                // lane<32 / lane>=32 half exchange: one permlane32_swap yields
                // both output words (f.u[0]=[a0.lo;a2.lo], f.u[2]=[a0.hi;a2.hi])
                auto s02 = __builtin_amdgcn_permlane32_swap(
                    up[kh * 4 + 0], up[kh * 4 + 2], false, false);
                auto s13 = __builtin_amdgcn_permlane32_swap(
                    up[kh * 4 + 1], up[kh * 4 + 3], false, false);
                union { short8 s; unsigned u[4]; } f;
                f.u[0] = s02[0];
                f.u[1] = s13[0];
                f.u[2] = s02[1];
                f.u[3] = s13[1];
                const int kp = mt * 2 + kh;
#pragma unroll
                for (int dt = 0; dt < 2; ++dt) {
                    short8 av = *(const short8*)&KV[g][cur][1][(dt * 32 + col) * 72 + kp * 16 + hi * 8];
                    o_[dt] = __builtin_amdgcn_mfma_f32_32x32x16_bf16(av, f.s, o_[dt], 0, 0, 0);
                }
            }
            __builtin_amdgcn_s_setprio(0);
        }

        if (kt < 7) {
            const int nxt = cur ^ 1;
            *(uint4*)&KV[g][nxt][0][la0] = k0;  *(uint4*)&KV[g][nxt][0][la1] = k1;
            *(uint4*)&KV[g][nxt][1][la0] = v0;  *(uint4*)&KV[g][nxt][1][la1] = v1;
        }
        __syncthreads();
    }

    // ---- cross-group combine (reuse KV LDS; all tile reads done) ----
    float* xo  = (float*)&KV[0][0][0][0];         // 4 waves x 64 lanes x 36 f32
    float* lsx = xo + 4 * 64 * 36;                // + 256 f32  (38.9 KB total)
    if (g == 1) {
        float* dst = &xo[(wq * 64 + lane) * 36];
#pragma unroll
        for (int dt = 0; dt < 2; ++dt)
#pragma unroll
            for (int r4 = 0; r4 < 4; ++r4) {
                float4 o4 = make_float4(o_[dt][r4 * 4 + 0], o_[dt][r4 * 4 + 1],
                                        o_[dt][r4 * 4 + 2], o_[dt][r4 * 4 + 3]);
                *(float4*)&dst[dt * 16 + r4 * 4] = o4;
            }
        lsx[wq * 64 + lane] = ls;
    }
    __syncthreads();
    if (g == 0) {
        const float* src = &xo[(wq * 64 + lane) * 36];
        const float lt = ls + lsx[wq * 64 + lane];
        const float l  = lt + (float)__shfl_xor(lt, 32, 64);
        const float inv = 1.0f / l;
        const int q = qt * 128 + wq * 32 + col;
        float* op = &out[((size_t)b * Sn + q) * Dn + h * 64];
#pragma unroll
        for (int dt = 0; dt < 2; ++dt)
#pragma unroll
            for (int rg = 0; rg < 4; ++rg) {
                float4 s4 = *(const float4*)&src[dt * 16 + rg * 4];
                const int d = dt * 32 + rg * 8 + hi * 4;
                float4 o4;
                o4.x = fmaxf((o_[dt][rg * 4 + 0] + s4.x) * inv, 0.0f);
                o4.y = fmaxf((o_[dt][rg * 4 + 1] + s4.y) * inv, 0.0f);
                o4.z = fmaxf((o_[dt][rg * 4 + 2] + s4.z) * inv, 0.0f);
                o4.w = fmaxf((o_[dt][rg * 4 + 3] + s4.w) * inv, 0.0f);
                *(float4*)&op[d] = o4;
            }
    }
}

extern "C" void kernel_launch(void* const* d_in, const int* in_sizes, int n_in,
                              void* d_out, int out_size, void* d_ws, size_t ws_size,
                              hipStream_t stream)
{
    const float* x   = (const float*)d_in[0];
    const float* adj = (const float*)d_in[1];
    const float* Wq  = (const float*)d_in[2];
    const float* bq  = (const float*)d_in[3];
    const float* Wk  = (const float*)d_in[4];
    const float* bk  = (const float*)d_in[5];
    const float* Wv  = (const float*)d_in[6];
    const float* bv  = (const float*)d_in[7];
    float* out = (float*)d_out;

    // ws (ushort): xb[4.19M] | Wt[3.15M] | Qb | Kb | Vb [4.19M ea] then Mb (uint, 8.4 MB)
    ushort* xb = (ushort*)d_ws;
    ushort* Wt = xb + (size_t)Bn * Sn * Dn;
    ushort* Qb = Wt + (size_t)3 * Dn * Dn;
    ushort* Kb = Qb + (size_t)Bn * Hn * Sn * HDn;
    ushort* Vb = Kb + (size_t)Bn * Hn * Sn * HDn;
    uint*   Mb = (uint*)(Vb + (size_t)Bn * Hn * Sn * HDn);

    prep<<<dim3(3328), 256, 0, stream>>>(x, Wq, Wk, Wv, adj, xb, Wt, Mb, out);

    qkv_gemm<<<dim3(768), 256, 0, stream>>>(xb, Wt, bq, bk, bv, Qb, Kb, Vb);

    attn_mfma<<<dim3(512), 512, 0, stream>>>(Qb, Kb, Vb, Mb, out);
}

// Round 8
// 175.119 us; speedup vs baseline: 1.2985x; 1.2985x over previous
//
#include <hip/hip_runtime.h>

constexpr int Bn  = 4;
constexpr int Sn  = 1024;
constexpr int Dn  = 1024;
constexpr int Hn  = 16;
constexpr int HDn = 64;

using short8   = __attribute__((ext_vector_type(8))) short;
using float4v  = __attribute__((ext_vector_type(4))) float;
using float16v = __attribute__((ext_vector_type(16))) float;

__device__ __forceinline__ ushort f2bf(float f) {
    union { float f; unsigned u; } v; v.f = f;
    unsigned r = v.u + 0x7fff + ((v.u >> 16) & 1);   // RNE
    return (ushort)(r >> 16);
}

__device__ __forceinline__ void gload16(const void* g, void* l) {
    __builtin_amdgcn_global_load_lds(
        (const __attribute__((address_space(1))) void*)g,
        (__attribute__((address_space(3))) void*)l, 16, 0, 0);
}

// ---------------------------------------------------------------------------
// prep — ONE dispatch, 3328 blocks, HEAVY BLOCKS FIRST:
//   [0,512)     mask+copy: adj -> out passthrough AND pair-halfword masks
//   [512,1280)  transpose_w: W (KxN fp32) -> Wt (NxK bf16), 64x64 LDS tiles
//   [1280,3328) convert_x: x fp32 -> xb bf16
// Mask pack (R18 fix): INTEGER pack (uint)a.x|((uint)a.y<<8)|((uint)a.z<<16)
// |((uint)a.w<<24) — R7's float-arithmetic pack (a.x+256a.y+65536a.z+2^24a.w)
// was NOT exact: 2^24+..+1 needs 25 mantissa bits, RNE dropped low bits
// (absmax 0.457 fail). Integer cvt+or is exact; still ONE ds_write_b32 per
// float4 and one u16 ds_read per mask word (LDS ops/thread 64 -> 24).
// Mask layout (R7/R10-proven): dst = Mb + ((((b*8+qt)*16+kt)*4+w)*64+lane)*16;
// word mt*8+pr covers keys kt*64+mt*32+(2pr&3)+8*(2pr>>2)+4*hi+{0,1},
// q = qt*128+w*32+(lane&31).
// ---------------------------------------------------------------------------
__global__ __launch_bounds__(256) void prep(
    const float* __restrict__ x,
    const float* __restrict__ Wq, const float* __restrict__ Wk,
    const float* __restrict__ Wv, const float* __restrict__ adj,
    ushort* __restrict__ xb, ushort* __restrict__ Wt, uint* __restrict__ Mb,
    float* __restrict__ out)
{
    const int bx  = blockIdx.x;
    const int tid = threadIdx.x;
    __shared__ __align__(16) ushort pool[64 * 72];   // 9216 B, aliased by msk

    if (bx < 512) {
        // ---- mask + adj->out copy: idx = ((b*8+qt)*16+kt) ----
        const int idx = bx;                        // 0..511
        const int kt = idx & 15, qt = (idx >> 4) & 7, b = idx >> 7;
        char* msk = (char*)pool;                   // [128][68], 8704 B <= 9216

        float* ocopy = out + (size_t)Bn * Sn * Dn;
        const int r16 = tid >> 4, c4 = (tid & 15) * 4;
#pragma unroll
        for (int p = 0; p < 8; ++p) {
            const int row = p * 16 + r16;
            const size_t gi = ((size_t)b * Sn + qt * 128 + row) * Sn + kt * 64 + c4;
            float4 a = *(const float4*)&adj[gi];
            *(float4*)&ocopy[gi] = a;
            // adj in {0.0,1.0} exactly -> integer byte-pack (exact)
            const uint pk = (uint)a.x | ((uint)a.y << 8) |
                            ((uint)a.z << 16) | ((uint)a.w << 24);
            *(uint*)&msk[row * 68 + c4] = pk;
        }
        __syncthreads();

        const int lane = tid & 63, w = tid >> 6;
        const int col = lane & 31, hi = lane >> 5;
        const char* mr = &msk[(w * 32 + col) * 68];
        uint words[16];
#pragma unroll
        for (int mt = 0; mt < 2; ++mt)
#pragma unroll
            for (int pr = 0; pr < 8; ++pr) {
                const int r0 = 2 * pr;
                const int kl = mt * 32 + (r0 & 3) + 8 * (r0 >> 2) + 4 * hi; // even
                const uint m2 = *(const ushort*)&mr[kl];   // bytes {0,1}
                // bit0 -> 0x0000FFFF, bit8 -> 0xFFFF0000
                words[mt * 8 + pr] = ((m2 & 1u) | ((m2 & 0x100u) << 8)) * 0xFFFFu;
            }
        uint* dst = Mb + ((((size_t)(b * 8 + qt) * 16 + kt) * 4 + w) * 64 + lane) * 16;
#pragma unroll
        for (int c = 0; c < 4; ++c)
            *(uint4*)&dst[c * 4] =
                make_uint4(words[c*4], words[c*4+1], words[c*4+2], words[c*4+3]);
    } else if (bx < 1280) {
        // ---- transpose_w ----
        const int idx = bx - 512;
        const int which = idx >> 8, rem = idx & 255;
        const float* __restrict__ W = (which == 0) ? Wq : (which == 1) ? Wk : Wv;
        ushort* __restrict__ O = Wt + (size_t)which * Dn * Dn;
        const int k0 = (rem & 15) * 64, n0 = (rem >> 4) * 64;
        ushort* T = pool;

        const int kl = tid >> 4, nl = (tid & 15) * 4;
#pragma unroll
        for (int p = 0; p < 4; ++p) {
            float4 w4 = *(const float4*)&W[(size_t)(k0 + p * 16 + kl) * Dn + n0 + nl];
            T[(nl + 0) * 72 + p * 16 + kl] = f2bf(w4.x);
            T[(nl + 1) * 72 + p * 16 + kl] = f2bf(w4.y);
            T[(nl + 2) * 72 + p * 16 + kl] = f2bf(w4.z);
            T[(nl + 3) * 72 + p * 16 + kl] = f2bf(w4.w);
        }
        __syncthreads();
        const int nr = tid >> 2, kc = (tid & 3) * 16;
        uint4 u0 = *(const uint4*)&T[nr * 72 + kc];
        uint4 u1 = *(const uint4*)&T[nr * 72 + kc + 8];
        *(uint4*)&O[(size_t)(n0 + nr) * Dn + k0 + kc]     = u0;
        *(uint4*)&O[(size_t)(n0 + nr) * Dn + k0 + kc + 8] = u1;
    } else {
        // ---- convert_x ----
        const size_t i = ((size_t)(bx - 1280) * 256 + tid) * 8;
        float4 a = *(const float4*)&x[i];
        float4 b = *(const float4*)&x[i + 4];
        ushort o[8] = {f2bf(a.x), f2bf(a.y), f2bf(a.z), f2bf(a.w),
                       f2bf(b.x), f2bf(b.y), f2bf(b.z), f2bf(b.w)};
        *(uint4*)&xb[i] = *(const uint4*)o;
    }
}

// ---------------------------------------------------------------------------
// bf16 MFMA GEMM (R15 proven, 43.0 µs): 3-buffer distance-2 pipeline, counted
// vmcnt (T3+T4). Per step: wait vmcnt(8) (tile k landed), barrier, ds_read,
// lgkmcnt(0)+barrier (buf free), restage tile k+3 into buf cur, MFMA.
// Tail peeled vmcnt(8/4/0). LDS 48 KB -> 3 blocks/CU.
// PLATEAU NOTE (R3-R6): four structures (2-barrier, dbuf-1, this, B-direct)
// give 43/45/43/92 µs -> ~600 TF is this shape's 128²-structure ceiling
// (m102 shape curve). Do not retune the schedule.
//  - LDS chunk-XOR swizzle (conflicts measured 0).
//  - XCD-chunked 1D grid (768): each XCD owns 4 contiguous A-panels (by).
//  - R6 lesson: do NOT bypass LDS for B — B panels span XCDs, FETCH +26 MB.
// ---------------------------------------------------------------------------
__global__ __launch_bounds__(256) void qkv_gemm(
    const ushort* __restrict__ xb, const ushort* __restrict__ Wt,
    const float* __restrict__ bq, const float* __restrict__ bk,
    const float* __restrict__ bv,
    ushort* __restrict__ Qb, ushort* __restrict__ Kb, ushort* __restrict__ Vb)
{
    const int n  = blockIdx.x;                // 0..767
    const int v  = (n & 7) * 96 + (n >> 3);
    const int by = v / 24;                    // 0..31
    const int rr = v - by * 24;
    const int bxi   = rr & 7;                 // 0..7
    const int which = rr >> 3;                // 0..2

    const ushort* __restrict__ Bw   = Wt + (size_t)which * Dn * Dn;
    const float* __restrict__  bias = (which == 0) ? bq : (which == 1) ? bk : bv;
    ushort* __restrict__       Out  = (which == 0) ? Qb : (which == 1) ? Kb : Vb;
    const float scale = (which == 0) ? 0.18033688011112042f : 1.0f;  // 0.125*log2(e)

    const int n0   = bxi * 128;
    const int m0   = by * 128;
    const int tid  = threadIdx.x;
    const int wave = tid >> 6;
    const int lane = tid & 63;
    const int wm   = wave >> 1;
    const int wn   = wave & 1;

    __shared__ __align__(16) ushort As[3][128 * 32];
    __shared__ __align__(16) ushort Bs[3][128 * 32];

    const int L0 = wave * 64 + lane;
    const int r0s = L0 >> 2, c0s = ((L0 & 3) ^ ((L0 >> 3) & 3)) * 8;  // swizzled src chunk
    const int L1 = L0 + 256;
    const int r1s = L1 >> 2, c1s = ((L1 & 3) ^ ((L1 >> 3) & 3)) * 8;

    const ushort* pA0 = &xb[(size_t)(m0 + r0s) * Dn + c0s];
    const ushort* pA1 = &xb[(size_t)(m0 + r1s) * Dn + c1s];
    const ushort* pB0 = &Bw[(size_t)(n0 + r0s) * Dn + c0s];
    const ushort* pB1 = &Bw[(size_t)(n0 + r1s) * Dn + c1s];

    const int mlane = lane & 15;
    const int kg = (((lane >> 4) ^ ((mlane >> 1) & 3))) * 8;

    float4v acc[4][4];
    const float4v z4 = {0.f, 0.f, 0.f, 0.f};
#pragma unroll
    for (int i = 0; i < 4; ++i)
#pragma unroll
        for (int j = 0; j < 4; ++j) acc[i][j] = z4;

    auto stage = [&](int c) {
        char* ab = (char*)As + c * 8192 + wave * 1024;
        char* bb = (char*)Bs + c * 8192 + wave * 1024;
        gload16(pA0, ab);
        gload16(pA1, ab + 4096);
        gload16(pB0, bb);
        gload16(pB1, bb + 4096);
        pA0 += 32; pA1 += 32; pB0 += 32; pB1 += 32;
    };
    auto ldsread = [&](int c, short8 (&af)[4], short8 (&bf)[4]) {
#pragma unroll
        for (int i = 0; i < 4; ++i)
            af[i] = *(const short8*)&As[c][(wm * 64 + i * 16 + mlane) * 32 + kg];
#pragma unroll
        for (int j = 0; j < 4; ++j)
            bf[j] = *(const short8*)&Bs[c][(wn * 64 + j * 16 + mlane) * 32 + kg];
    };
    auto domfma = [&](short8 (&af)[4], short8 (&bf)[4]) {
        __builtin_amdgcn_s_setprio(1);
#pragma unroll
        for (int i = 0; i < 4; ++i)
#pragma unroll
            for (int j = 0; j < 4; ++j)
                acc[i][j] = __builtin_amdgcn_mfma_f32_16x16x32_bf16(af[i], bf[j], acc[i][j], 0, 0, 0);
        __builtin_amdgcn_s_setprio(0);
    };

    stage(0); stage(1); stage(2);

    constexpr int NT = Dn / 32;     // 32 K-steps
    int cur = 0;
    for (int k = 0; k < NT - 3; ++k) {           // 29 iters; stages tiles 3..31
        asm volatile("s_waitcnt vmcnt(8)" ::: "memory");   // tile k landed (own)
        __builtin_amdgcn_s_barrier();                      // ...for all waves
        short8 af[4], bf[4];
        ldsread(cur, af, bf);
        asm volatile("s_waitcnt lgkmcnt(0)" ::: "memory"); // own reads retired
        __builtin_amdgcn_sched_barrier(0);
        __builtin_amdgcn_s_barrier();                      // buf cur free (all)
        __builtin_amdgcn_sched_barrier(0);
        stage(cur);                                        // tile k+3 -> buf cur
        domfma(af, bf);                                    // overlaps 8 in-flight loads
        cur = (cur == 2) ? 0 : cur + 1;
    }
    {
        asm volatile("s_waitcnt vmcnt(8)" ::: "memory");
        __builtin_amdgcn_s_barrier();
        short8 af[4], bf[4];
        ldsread(cur, af, bf);
        domfma(af, bf);
        cur = (cur == 2) ? 0 : cur + 1;
    }
    {
        asm volatile("s_waitcnt vmcnt(4)" ::: "memory");
        __builtin_amdgcn_s_barrier();
        short8 af[4], bf[4];
        ldsread(cur, af, bf);
        domfma(af, bf);
        cur = (cur == 2) ? 0 : cur + 1;
    }
    {
        asm volatile("s_waitcnt vmcnt(0)" ::: "memory");
        __builtin_amdgcn_s_barrier();
        short8 af[4], bf[4];
        ldsread(cur, af, bf);
        domfma(af, bf);
    }

    const int rb  = (lane >> 4) * 4;
    const int col = lane & 15;
#pragma unroll
    for (int j = 0; j < 4; ++j) {
        const int nn = n0 + wn * 64 + j * 16 + col;
        const float bias_n = bias[nn];
        const int h  = nn >> 6;
        const int hd = nn & 63;
#pragma unroll
        for (int i = 0; i < 4; ++i) {
#pragma unroll
            for (int r = 0; r < 4; ++r) {
                const int m = m0 + wm * 64 + i * 16 + rb + r;
                const int b = m >> 10;
                const int s = m & 1023;
                size_t addr;
                if (which == 2)
                    addr = (((size_t)(b * Hn + h)) * HDn + hd) * Sn + s;   // V transposed
                else
                    addr = (((size_t)(b * Hn + h)) * Sn + s) * HDn + hd;
                Out[addr] = f2bf((acc[i][j][r] + bias_n) * scale);
            }
        }
    }
}

// ---------------------------------------------------------------------------
// MFMA flash attention, split-K over keys:
// Block = 512 threads (8 waves) = 128 q of one (b,h).
//   waves 0-3 (group 0): keys   0..511; waves 4-7 (group 1): keys 512..1023
// Mask loaded at top of each kt iteration (independent load, latency covered
// by QK^T cluster — R2's explicit one-ahead prefetch caused ~96 MB/dispatch
// of scratch-spill WRITE traffic and a 25 µs regression; do NOT re-add).
// Pack via v_permlane32_swap_b32; s_setprio(1) around MFMA clusters (T5).
// Cross-group combine via one LDS exchange (exp2 softmax has no running
// max -> pure (o,l) add). XCD swizzle: co-(b,h) blocks share an XCD L2.
// ---------------------------------------------------------------------------
__global__ __launch_bounds__(512, 4) void attn_mfma(
    const ushort* __restrict__ Q, const ushort* __restrict__ K,
    const ushort* __restrict__ Vt, const uint* __restrict__ Mw,
    float* __restrict__ out)
{
    const int n  = blockIdx.x;                 // 0..511
    const int qt = (n >> 3) & 7;
    const int bh = (n & 7) | ((n >> 6) << 3);  // 0..63
    const int h  = bh & 15;
    const int b  = bh >> 4;

    const int tid  = threadIdx.x;
    const int w    = tid >> 6, lane = tid & 63;
    const int g    = w >> 2;                   // key-half group
    const int wq   = w & 3;                    // q-subtile within block
    const int col  = lane & 31, hi = lane >> 5;

    const size_t hb = ((size_t)(b * Hn + h)) * Sn * HDn;
    const ushort* Kg = K + hb;          // [key][dim]
    const ushort* Vg = Vt + hb;         // [dim][key]

    __shared__ __align__(16) ushort KV[2][2][2][64 * 72];

    short8 qf[4];
#pragma unroll
    for (int kp = 0; kp < 4; ++kp)
        qf[kp] = *(const short8*)&Q[hb +
            (size_t)(qt * 128 + wq * 32 + col) * HDn + kp * 16 + hi * 8];

    float16v o_[2];
#pragma unroll
    for (int dt = 0; dt < 2; ++dt)
#pragma unroll
        for (int r = 0; r < 16; ++r) o_[dt][r] = 0.f;
    float ls = 0.f;

    const int t  = tid & 255;
    const int c0 = t, c1 = t + 256;
    const int la0 = (c0 >> 3) * 72 + (c0 & 7) * 8;
    const int la1 = (c1 >> 3) * 72 + (c1 & 7) * 8;
    const int kb  = g * 8;                     // first key-tile of this group

    uint4 k0 = *(const uint4*)&Kg[(size_t)(kb * 64 + (c0 >> 3)) * HDn + (c0 & 7) * 8];
    uint4 k1 = *(const uint4*)&Kg[(size_t)(kb * 64 + (c1 >> 3)) * HDn + (c1 & 7) * 8];
    uint4 v0 = *(const uint4*)&Vg[(size_t)(c0 >> 3) * Sn + kb * 64 + (c0 & 7) * 8];
    uint4 v1 = *(const uint4*)&Vg[(size_t)(c1 >> 3) * Sn + kb * 64 + (c1 & 7) * 8];
    *(uint4*)&KV[g][0][0][la0] = k0;  *(uint4*)&KV[g][0][0][la1] = k1;
    *(uint4*)&KV[g][0][1][la0] = v0;  *(uint4*)&KV[g][0][1][la1] = v1;
    __syncthreads();

    const uint* mbase = Mw + ((size_t)((b * 8 + qt) * 16) * 4 + wq) * 1024 + lane * 16;

    for (int kt = 0; kt < 8; ++kt) {
        const int cur = kt & 1;
        if (kt < 7) {
            const int nk = (kb + kt + 1) * 64;
            k0 = *(const uint4*)&Kg[(size_t)(nk + (c0 >> 3)) * HDn + (c0 & 7) * 8];
            k1 = *(const uint4*)&Kg[(size_t)(nk + (c1 >> 3)) * HDn + (c1 & 7) * 8];
            v0 = *(const uint4*)&Vg[(size_t)(c0 >> 3) * Sn + nk + (c0 & 7) * 8];
            v1 = *(const uint4*)&Vg[(size_t)(c1 >> 3) * Sn + nk + (c1 & 7) * 8];
        }
        const uint* mp = mbase + (size_t)(kb + kt) * 4096;
        uint4 mk4[4];
        mk4[0] = *(const uint4*)(mp);
        mk4[1] = *(const uint4*)(mp + 4);
        mk4[2] = *(const uint4*)(mp + 8);
        mk4[3] = *(const uint4*)(mp + 12);
        const uint* mka = (const uint*)mk4;   // [mt*8 + pr]

#pragma unroll
        for (int mt = 0; mt < 2; ++mt) {
            float16v s_;
#pragma unroll
            for (int r = 0; r < 16; ++r) s_[r] = 0.f;
            __builtin_amdgcn_s_setprio(1);
#pragma unroll
            for (int kp = 0; kp < 4; ++kp) {
                short8 ak = *(const short8*)&KV[g][cur][0][(mt * 32 + col) * 72 + kp * 16 + hi * 8];
                s_ = __builtin_amdgcn_mfma_f32_32x32x16_bf16(ak, qf[kp], s_, 0, 0, 0);
            }
            __builtin_amdgcn_s_setprio(0);

            unsigned up[8];
#pragma unroll
            for (int pr = 0; pr < 8; ++pr) {
                const unsigned e0 = __float_as_uint(exp2f(s_[2 * pr]))     + 0x8000u;
                const unsigned e1 = __float_as_uint(exp2f(s_[2 * pr + 1])) + 0x8000u;
                const unsigned u  = __builtin_amdgcn_perm(e1, e0, 0x07060302u) & mka[mt * 8 + pr];
                up[pr] = u;
                ls += __uint_as_float(u << 16) + __uint_as_float(u & 0xffff0000u);
            }

            __builtin_amdgcn_s_setprio(1);
#pragma unroll
            for (int kh = 0; kh < 2; ++kh) {
                auto s02 = __builtin_amdgcn_permlane32_swap(
                    up[kh * 4 + 0], up[kh * 4 + 2], false, false);
                auto s13 = __builtin_amdgcn_permlane32_swap(
                    up[kh * 4 + 1], up[kh * 4 + 3], false, false);
                union { short8 s; unsigned u[4]; } f;
                f.u[0] = s02[0];
                f.u[1] = s13[0];
                f.u[2] = s02[1];
                f.u[3] = s13[1];
                const int kp = mt * 2 + kh;
#pragma unroll
                for (int dt = 0; dt < 2; ++dt) {
                    short8 av = *(const short8*)&KV[g][cur][1][(dt * 32 + col) * 72 + kp * 16 + hi * 8];
                    o_[dt] = __builtin_amdgcn_mfma_f32_32x32x16_bf16(av, f.s, o_[dt], 0, 0, 0);
                }
            }
            __builtin_amdgcn_s_setprio(0);
        }

        if (kt < 7) {
            const int nxt = cur ^ 1;
            *(uint4*)&KV[g][nxt][0][la0] = k0;  *(uint4*)&KV[g][nxt][0][la1] = k1;
            *(uint4*)&KV[g][nxt][1][la0] = v0;  *(uint4*)&KV[g][nxt][1][la1] = v1;
        }
        __syncthreads();
    }

    // ---- cross-group combine (reuse KV LDS; all tile reads done) ----
    float* xo  = (float*)&KV[0][0][0][0];         // 4 waves x 64 lanes x 36 f32
    float* lsx = xo + 4 * 64 * 36;                // + 256 f32  (38.9 KB total)
    if (g == 1) {
        float* dst = &xo[(wq * 64 + lane) * 36];
#pragma unroll
        for (int dt = 0; dt < 2; ++dt)
#pragma unroll
            for (int r4 = 0; r4 < 4; ++r4) {
                float4 o4 = make_float4(o_[dt][r4 * 4 + 0], o_[dt][r4 * 4 + 1],
                                        o_[dt][r4 * 4 + 2], o_[dt][r4 * 4 + 3]);
                *(float4*)&dst[dt * 16 + r4 * 4] = o4;
            }
        lsx[wq * 64 + lane] = ls;
    }
    __syncthreads();
    if (g == 0) {
        const float* src = &xo[(wq * 64 + lane) * 36];
        const float lt = ls + lsx[wq * 64 + lane];
        const float l  = lt + (float)__shfl_xor(lt, 32, 64);
        const float inv = 1.0f / l;
        const int q = qt * 128 + wq * 32 + col;
        float* op = &out[((size_t)b * Sn + q) * Dn + h * 64];
#pragma unroll
        for (int dt = 0; dt < 2; ++dt)
#pragma unroll
            for (int rg = 0; rg < 4; ++rg) {
                float4 s4 = *(const float4*)&src[dt * 16 + rg * 4];
                const int d = dt * 32 + rg * 8 + hi * 4;
                float4 o4;
                o4.x = fmaxf((o_[dt][rg * 4 + 0] + s4.x) * inv, 0.0f);
                o4.y = fmaxf((o_[dt][rg * 4 + 1] + s4.y) * inv, 0.0f);
                o4.z = fmaxf((o_[dt][rg * 4 + 2] + s4.z) * inv, 0.0f);
                o4.w = fmaxf((o_[dt][rg * 4 + 3] + s4.w) * inv, 0.0f);
                *(float4*)&op[d] = o4;
            }
    }
}

extern "C" void kernel_launch(void* const* d_in, const int* in_sizes, int n_in,
                              void* d_out, int out_size, void* d_ws, size_t ws_size,
                              hipStream_t stream)
{
    const float* x   = (const float*)d_in[0];
    const float* adj = (const float*)d_in[1];
    const float* Wq  = (const float*)d_in[2];
    const float* bq  = (const float*)d_in[3];
    const float* Wk  = (const float*)d_in[4];
    const float* bk  = (const float*)d_in[5];
    const float* Wv  = (const float*)d_in[6];
    const float* bv  = (const float*)d_in[7];
    float* out = (float*)d_out;

    // ws (ushort): xb[4.19M] | Wt[3.15M] | Qb | Kb | Vb [4.19M ea] then Mb (uint, 8.4 MB)
    ushort* xb = (ushort*)d_ws;
    ushort* Wt = xb + (size_t)Bn * Sn * Dn;
    ushort* Qb = Wt + (size_t)3 * Dn * Dn;
    ushort* Kb = Qb + (size_t)Bn * Hn * Sn * HDn;
    ushort* Vb = Kb + (size_t)Bn * Hn * Sn * HDn;
    uint*   Mb = (uint*)(Vb + (size_t)Bn * Hn * Sn * HDn);

    prep<<<dim3(3328), 256, 0, stream>>>(x, Wq, Wk, Wv, adj, xb, Wt, Mb, out);

    qkv_gemm<<<dim3(768), 256, 0, stream>>>(xb, Wt, bq, bk, bv, Qb, Kb, Vb);

    attn_mfma<<<dim3(512), 512, 0, stream>>>(Qb, Kb, Vb, Mb, out);
}